// Round 12
// baseline (1484.238 us; speedup 1.0000x reference)
//
#include <hip/hip_runtime.h>
#include <math.h>

#define B_ 8
#define N_ 1024
#define D_ 512
#define H_ 4
#define ND (N_ * D_)      // 524288
#define DD (D_ * D_)      // 262144
#define NN (N_ * N_)      // 1048576
#define NBLK 1024u

typedef _Float16 f16;
typedef f16 f16x8 __attribute__((ext_vector_type(8)));
typedef float f32x4 __attribute__((ext_vector_type(4)));

typedef __attribute__((address_space(3))) void lds_void;
typedef __attribute__((address_space(1))) void g_void;

// Monotonic grid barrier. SAFETY: grid=1024, __launch_bounds__(256,4),
// 32 KB LDS => 4 blocks/CU * 256 CU = 1024 slots = grid, so all blocks
// are co-resident by construction (no block can be queued behind another).
__device__ __forceinline__ void grid_barrier(unsigned* ctr, unsigned target) {
    __syncthreads();                       // all block work done (vmcnt drained)
    if (threadIdx.x == 0) {
        __threadfence();                   // release: flush to device scope
        atomicAdd(ctr, 1u);
        while (__hip_atomic_load(ctr, __ATOMIC_RELAXED, __HIP_MEMORY_SCOPE_AGENT) < target)
            __builtin_amdgcn_s_sleep(4);
        __threadfence();                   // acquire: invalidate stale caches
    }
    __syncthreads();
}

// ---- single-tile core (g2): one 128x128 C-tile, 16 KB of pool ----
template<int LDA, int LDB, int LDC, int KTOT>
__device__ __forceinline__ void single_core(
    f16* __restrict__ sm,
    const f16* __restrict__ A, const f16* __restrict__ B0,
    f16* __restrict__ Ch, float scale, int n0, int c0)
{
    f16* sA  = sm;
    f16* sB0 = sm + 4096;

    const int t = threadIdx.x;
    const int w = t >> 6;
    const int l = t & 63;
    const int lrow = l >> 2;
    const int lch  = l & 3;
    const int wr = w >> 1, wc = w & 1;
    const int fr = l & 15;
    const int fq = l >> 4;

    f32x4 acc[4][4] = {};

    for (int k0 = 0; k0 < KTOT; k0 += 32) {
#pragma unroll
        for (int i = 0; i < 2; ++i) {
            const int rb  = w * 2 + i;
            const int row = rb * 16 + lrow;
            const f16* ga = A + (size_t)(n0 + row) * LDA + k0 + lch * 8;
            __builtin_amdgcn_global_load_lds((g_void*)ga, (lds_void*)(sA + rb * 512), 16, 0, 0);
            const f16* gb0 = B0 + (size_t)(c0 + row) * LDB + k0 + lch * 8;
            __builtin_amdgcn_global_load_lds((g_void*)gb0, (lds_void*)(sB0 + rb * 512), 16, 0, 0);
        }
        __syncthreads();

        f16x8 a[4], b0[4];
#pragma unroll
        for (int i = 0; i < 4; ++i) {
            a[i]  = *(const f16x8*)(sA  + (wr * 64 + i * 16 + fr) * 32 + fq * 8);
            b0[i] = *(const f16x8*)(sB0 + (wc * 64 + i * 16 + fr) * 32 + fq * 8);
        }

#pragma unroll
        for (int i = 0; i < 4; ++i)
#pragma unroll
            for (int j = 0; j < 4; ++j)
                acc[i][j] = __builtin_amdgcn_mfma_f32_16x16x32_f16(a[i], b0[j], acc[i][j], 0, 0, 0);
        __syncthreads();
    }

#pragma unroll
    for (int i = 0; i < 4; ++i)
#pragma unroll
        for (int j = 0; j < 4; ++j)
#pragma unroll
            for (int r = 0; r < 4; ++r) {
                const int row = n0 + wr * 64 + i * 16 + fq * 4 + r;
                const int col = c0 + wc * 64 + j * 16 + fr;
                Ch[(size_t)row * LDC + col] = (f16)(acc[i][j][r] * scale);
            }
}

// ---- paired-tile core (g1/g4): TWO stacked 128x128 C-tiles sharing B ----
template<int NPROD, int LDA, int LDB, int LDC, int KTOT>
__device__ __forceinline__ void pair_core(
    f16* __restrict__ sm,
    const f16* __restrict__ A, const f16* __restrict__ B0,
    const f16* __restrict__ B1, f16* __restrict__ Ch, int n0, int c0)
{
    f16* sA  = sm;
    f16* sB0 = sm + 8192;
    f16* sB1 = sm + 12288;

    const int t = threadIdx.x;
    const int w = t >> 6;
    const int l = t & 63;
    const int lrow = l >> 2;
    const int lch  = l & 3;
    const int wr = w >> 1, wc = w & 1;
    const int fr = l & 15;
    const int fq = l >> 4;

    f32x4 acc0[4][4] = {};
    f32x4 acc1[4][4] = {};

    for (int k0 = 0; k0 < KTOT; k0 += 32) {
#pragma unroll
        for (int i = 0; i < 4; ++i) {
            const int rb  = w * 4 + i;
            const int row = rb * 16 + lrow;
            const f16* ga = A + (size_t)(n0 + row) * LDA + k0 + lch * 8;
            __builtin_amdgcn_global_load_lds((g_void*)ga, (lds_void*)(sA + rb * 512), 16, 0, 0);
        }
#pragma unroll
        for (int i = 0; i < 2; ++i) {
            const int rb  = w * 2 + i;
            const int row = rb * 16 + lrow;
            const f16* gb0 = B0 + (size_t)(c0 + row) * LDB + k0 + lch * 8;
            __builtin_amdgcn_global_load_lds((g_void*)gb0, (lds_void*)(sB0 + rb * 512), 16, 0, 0);
            if constexpr (NPROD == 2) {
                const f16* gb1 = B1 + (size_t)(c0 + row) * LDB + k0 + lch * 8;
                __builtin_amdgcn_global_load_lds((g_void*)gb1, (lds_void*)(sB1 + rb * 512), 16, 0, 0);
            }
        }
        __syncthreads();

        f16x8 a0[4], a1[4], b0[4], b1[4];
#pragma unroll
        for (int i = 0; i < 4; ++i) {
            a0[i] = *(const f16x8*)(sA + (wr * 64 + i * 16 + fr) * 32 + fq * 8);
            a1[i] = *(const f16x8*)(sA + (128 * 32) + (wr * 64 + i * 16 + fr) * 32 + fq * 8);
            b0[i] = *(const f16x8*)(sB0 + (wc * 64 + i * 16 + fr) * 32 + fq * 8);
            if constexpr (NPROD == 2)
                b1[i] = *(const f16x8*)(sB1 + (wc * 64 + i * 16 + fr) * 32 + fq * 8);
        }

#pragma unroll
        for (int i = 0; i < 4; ++i)
#pragma unroll
            for (int j = 0; j < 4; ++j) {
                acc0[i][j] = __builtin_amdgcn_mfma_f32_16x16x32_f16(a0[i], b0[j], acc0[i][j], 0, 0, 0);
                acc1[i][j] = __builtin_amdgcn_mfma_f32_16x16x32_f16(a1[i], b0[j], acc1[i][j], 0, 0, 0);
                if constexpr (NPROD == 2) {
                    acc0[i][j] = __builtin_amdgcn_mfma_f32_16x16x32_f16(a0[i], b1[j], acc0[i][j], 0, 0, 0);
                    acc1[i][j] = __builtin_amdgcn_mfma_f32_16x16x32_f16(a1[i], b1[j], acc1[i][j], 0, 0, 0);
                }
            }
        __syncthreads();
    }

#pragma unroll
    for (int i = 0; i < 4; ++i)
#pragma unroll
        for (int j = 0; j < 4; ++j)
#pragma unroll
            for (int r = 0; r < 4; ++r) {
                const int row = n0 + wr * 64 + i * 16 + fq * 4 + r;
                const int col = c0 + wc * 64 + j * 16 + fr;
                Ch[(size_t)row * LDC + col] = (f16)acc0[i][j][r];
                Ch[(size_t)(row + 128) * LDC + col] = (f16)acc1[i][j][r];
            }
}

// =====================================================================
// Mega-kernel, NORMAL launch + manual grid barrier. 1024 blocks x 256,
// 32 KB LDS pool, VGPR<=128 (launch_bounds 256,4) => exactly 4 blocks/CU
// co-resident. Phases = R8/R9 proven kernels.
// =====================================================================
__global__ void __launch_bounds__(256, 4) mega(
    const float* __restrict__ x, const float* __restrict__ W,
    f16* __restrict__ xfh, f16* __restrict__ xT,
    f16* __restrict__ wTh, f16* __restrict__ wTl,
    f16* __restrict__ Yh, f16* __restrict__ S, f16* __restrict__ P,
    float* __restrict__ out, unsigned* __restrict__ ctr)
{
    __shared__ f16 sm[16384];   // 32 KB pool
    const int blk = blockIdx.x;
    const int t = threadIdx.x;

    // ---------- phase 0: decomp x (all blocks) + W (blocks < 256) ----------
    {
        const int b = blk >> 7, rem = blk & 127;
        const int n0 = (rem >> 3) * 64, d0 = (rem & 7) * 64;
        const float* xb = x + (size_t)b * ND;
        f16* tile = sm;                        // [64][65] f16
#pragma unroll
        for (int p = 0; p < 16; ++p) {
            const int idx = t + p * 256;
            const int r = idx >> 6, c = idx & 63;
            const float v = xb[(size_t)(n0 + r) * D_ + d0 + c];
            const f16 h = (f16)v;
            xfh[(size_t)b * ND + (size_t)(n0 + r) * D_ + d0 + c] = h;
            tile[r * 65 + c] = h;
        }
        __syncthreads();
#pragma unroll
        for (int p = 0; p < 16; ++p) {
            const int idx = t + p * 256;
            const int r = idx >> 6, c = idx & 63;
            xT[(size_t)b * ND + (size_t)(d0 + r) * N_ + n0 + c] = tile[c * 65 + r];
        }
        if (blk < 256) {
            float* tw = (float*)(sm + 4160);   // disjoint region, [64][65] f32
            const int h = blk >> 6, rem2 = blk & 63;
            const int dd0 = (rem2 >> 3) * 64, e0 = (rem2 & 7) * 64;
            const float* Wh = W + (size_t)h * DD;
#pragma unroll
            for (int p = 0; p < 16; ++p) {
                const int idx = t + p * 256;
                const int r = idx >> 6, c = idx & 63;
                tw[r * 65 + c] = Wh[(size_t)(dd0 + r) * D_ + e0 + c];
            }
            __syncthreads();
#pragma unroll
            for (int p = 0; p < 16; ++p) {
                const int idx = t + p * 256;
                const int r = idx >> 6, c = idx & 63;
                const float v = tw[c * 65 + r];
                const f16 hh = (f16)v;
                const size_t o = (size_t)h * DD + (size_t)(e0 + r) * D_ + dd0 + c;
                wTh[o] = hh;
                wTl[o] = (f16)(v - (float)hh);
            }
        }
    }
    grid_barrier(ctr, NBLK * 1);

    // ---------- phase 1: g1 = Yh[z] = f16( x[b] @ (Wh+Wl)[h] ), paired ----------
    if (blk < 512) {
        const int b = blk & 7;
        const int li = blk >> 3;
        const int h = li >> 4;
        const int n0 = ((li >> 2) & 3) * 256;
        const int e0 = (li & 3) * 128;
        const int z = b * 4 + h;
        pair_core<2, D_, D_, D_, D_>(sm,
            xfh + (size_t)b * ND,
            wTh + (size_t)h * DD, wTl + (size_t)h * DD,
            Yh + (size_t)z * ND, n0, e0);
    }
    grid_barrier(ctr, NBLK * 2);

    // ---------- phase 2: g2, 2 tiles/block (xcd-stable) ----------
    for (int tt = 0; tt < 2; ++tt) {
        const int i = blk + tt * 1024;
        const int b = i & 7;
        const int li = i >> 3;
        const int h = li >> 6;
        const int n0 = ((li >> 3) & 7) * 128;
        const int m0 = (li & 7) * 128;
        const int z = b * 4 + h;
        single_core<D_, D_, N_, D_>(sm,
            Yh + (size_t)z * ND,
            xfh + (size_t)b * ND,
            S + (size_t)z * NN, 0.044194173824159216f, n0, m0);
    }
    grid_barrier(ctr, NBLK * 3);

    // ---------- phase 3: softmax, one wave per row, 8 rows/wave ----------
    {
        const int w = t >> 6, l = t & 63;
        const int gw = blk * 4 + w;
#pragma unroll
        for (int r8 = 0; r8 < 8; ++r8) {
            const size_t row = (size_t)gw * 8 + r8;
            const f16x8* p = (const f16x8*)(S + row * N_);
            f16x8 v0 = p[l * 2], v1 = p[l * 2 + 1];
            float f[16];
#pragma unroll
            for (int k = 0; k < 8; ++k) { f[k] = (float)v0[k]; f[k + 8] = (float)v1[k]; }
            float m = f[0];
#pragma unroll
            for (int k = 1; k < 16; ++k) m = fmaxf(m, f[k]);
#pragma unroll
            for (int o = 32; o > 0; o >>= 1) m = fmaxf(m, __shfl_xor(m, o));
            float s = 0.f;
#pragma unroll
            for (int k = 0; k < 16; ++k) { f[k] = __expf(f[k] - m); s += f[k]; }
#pragma unroll
            for (int o = 32; o > 0; o >>= 1) s += __shfl_xor(s, o);
            const float inv = 1.0f / s;
            f16x8 o0, o1;
#pragma unroll
            for (int k = 0; k < 8; ++k) {
                o0[k] = (f16)(f[k] * inv);
                o1[k] = (f16)(f[k + 8] * inv);
            }
            f16x8* q = (f16x8*)(P + row * N_);
            q[l * 2] = o0;
            q[l * 2 + 1] = o1;
        }
    }
    grid_barrier(ctr, NBLK * 4);

    // ---------- phase 4: g4 split-K by head, paired; partials into S ----------
    if (blk < 512) {
        const int b = blk & 7;
        const int li = blk >> 3;
        const int h = li >> 4;
        const int n0 = ((li >> 2) & 3) * 256;
        const int d0 = (li & 3) * 128;
        const int z = b * 4 + h;
        pair_core<1, N_, N_, D_, N_>(sm,
            P + (size_t)z * NN,
            xT + (size_t)b * ND, nullptr,
            S + (size_t)z * ND, n0, d0);   // part = S (dead after phase 3)
    }
    grid_barrier(ctr, NBLK * 5);

    // ---------- phase 5: reduce out[b] = 0.25 * sum_h part[b*4+h] ----------
    {
        const f16x8* p = (const f16x8*)S;
#pragma unroll
        for (int k2 = 0; k2 < 2; ++k2) {
            const int i = blk * 256 + t + k2 * 262144;
            const int b = i / (ND / 8);
            const int r = i - b * (ND / 8);
            f16x8 a0 = p[(size_t)(b * 4 + 0) * (ND / 8) + r];
            f16x8 a1 = p[(size_t)(b * 4 + 1) * (ND / 8) + r];
            f16x8 a2 = p[(size_t)(b * 4 + 2) * (ND / 8) + r];
            f16x8 a3 = p[(size_t)(b * 4 + 3) * (ND / 8) + r];
            float4 o0, o1;
            float* o = (float*)&o0;
#pragma unroll
            for (int k = 0; k < 4; ++k)
                o[k] = 0.25f * ((float)a0[k] + (float)a1[k] + (float)a2[k] + (float)a3[k]);
            o = (float*)&o1;
#pragma unroll
            for (int k = 0; k < 4; ++k)
                o[k] = 0.25f * ((float)a0[k+4] + (float)a1[k+4] + (float)a2[k+4] + (float)a3[k+4]);
            ((float4*)out)[(size_t)i * 2]     = o0;
            ((float4*)out)[(size_t)i * 2 + 1] = o1;
        }
    }
}

extern "C" void kernel_launch(void* const* d_in, const int* in_sizes, int n_in,
                              void* d_out, int out_size, void* d_ws, size_t ws_size,
                              hipStream_t stream) {
    const float* x = (const float*)d_in[0];   // [8,1024,512]
    const float* W = (const float*)d_in[1];   // [4,512,512]
    float* out = (float*)d_out;               // [8,1024,512]

    char* ws = (char*)d_ws;
    const size_t MB = 1024 * 1024;
    f16*   xfh = (f16*)(ws + 0 * MB);     // 8 MiB
    f16*   xT  = (f16*)(ws + 8 * MB);     // 8 MiB
    f16*   wTh = (f16*)(ws + 16 * MB);    // 2 MiB
    f16*   wTl = (f16*)(ws + 18 * MB);    // 2 MiB
    f16*   Yh  = (f16*)(ws + 20 * MB);    // 32 MiB
    f16*   S   = (f16*)(ws + 52 * MB);    // 64 MiB (also g4 partials)
    f16*   P   = (f16*)(ws + 116 * MB);   // 64 MiB
    unsigned* ctr = (unsigned*)(ws + 181 * MB);  // barrier counter

    hipMemsetAsync(ctr, 0, 64, stream);
    mega<<<dim3(NBLK), dim3(256), 0, stream>>>(
        x, W, xfh, xT, wTh, wTl, Yh, S, P, out, ctr);
}

// Round 13
// 214.935 us; speedup vs baseline: 6.9055x; 6.9055x over previous
//
#include <hip/hip_runtime.h>
#include <math.h>

#define B_ 8
#define N_ 1024
#define D_ 512
#define H_ 4
#define ND (N_ * D_)      // 524288
#define DD (D_ * D_)      // 262144
#define NN (N_ * N_)      // 1048576

typedef _Float16 f16;
typedef f16 f16x8 __attribute__((ext_vector_type(8)));
typedef float f32x4 __attribute__((ext_vector_type(4)));

typedef __attribute__((address_space(3))) void lds_void;
typedef __attribute__((address_space(1))) void g_void;

// =====================================================================
// R9-proven single-tile core: one 128x128 C-tile, BK=32, 16x16x32 f16
// MFMA, global_load_lds width-16, 2-barrier K-loop. EPI: f16*scale.
// =====================================================================
template<int LDA, int LDB, int LDC, int KTOT>
__device__ __forceinline__ void single_core(
    const f16* __restrict__ A, const f16* __restrict__ B0,
    f16* __restrict__ Ch, float scale, int n0, int c0)
{
    __shared__ f16 sA[128 * 32];
    __shared__ f16 sB0[128 * 32];

    const int t = threadIdx.x;
    const int w = t >> 6;
    const int l = t & 63;
    const int lrow = l >> 2;
    const int lch  = l & 3;
    const int wr = w >> 1, wc = w & 1;
    const int fr = l & 15;
    const int fq = l >> 4;

    f32x4 acc[4][4] = {};

    for (int k0 = 0; k0 < KTOT; k0 += 32) {
#pragma unroll
        for (int i = 0; i < 2; ++i) {
            const int rb  = w * 2 + i;
            const int row = rb * 16 + lrow;
            const f16* ga = A + (size_t)(n0 + row) * LDA + k0 + lch * 8;
            __builtin_amdgcn_global_load_lds((g_void*)ga, (lds_void*)(sA + rb * 512), 16, 0, 0);
            const f16* gb0 = B0 + (size_t)(c0 + row) * LDB + k0 + lch * 8;
            __builtin_amdgcn_global_load_lds((g_void*)gb0, (lds_void*)(sB0 + rb * 512), 16, 0, 0);
        }
        __syncthreads();

        f16x8 a[4], b0[4];
#pragma unroll
        for (int i = 0; i < 4; ++i) {
            a[i]  = *(const f16x8*)(sA  + (wr * 64 + i * 16 + fr) * 32 + fq * 8);
            b0[i] = *(const f16x8*)(sB0 + (wc * 64 + i * 16 + fr) * 32 + fq * 8);
        }

#pragma unroll
        for (int i = 0; i < 4; ++i)
#pragma unroll
            for (int j = 0; j < 4; ++j)
                acc[i][j] = __builtin_amdgcn_mfma_f32_16x16x32_f16(a[i], b0[j], acc[i][j], 0, 0, 0);
        __syncthreads();
    }

#pragma unroll
    for (int i = 0; i < 4; ++i)
#pragma unroll
        for (int j = 0; j < 4; ++j)
#pragma unroll
            for (int r = 0; r < 4; ++r) {
                const int row = n0 + wr * 64 + i * 16 + fq * 4 + r;
                const int col = c0 + wc * 64 + j * 16 + fr;
                Ch[(size_t)row * LDC + col] = (f16)(acc[i][j][r] * scale);
            }
}

// =====================================================================
// R8-proven paired-tile core: TWO stacked 128x128 C-tiles sharing the
// staged B tile. NPROD=1: 3 tiles staged -> 32 MFMA/wave. EPI: f16.
// =====================================================================
template<int NPROD, int LDA, int LDB, int LDC, int KTOT>
__device__ __forceinline__ void pair_core(
    const f16* __restrict__ A, const f16* __restrict__ B0,
    const f16* __restrict__ B1, f16* __restrict__ Ch, int n0, int c0)
{
    __shared__ f16 sA[256 * 32];
    __shared__ f16 sB0[128 * 32];
    __shared__ f16 sB1[(NPROD == 2) ? 128 * 32 : 64];

    const int t = threadIdx.x;
    const int w = t >> 6;
    const int l = t & 63;
    const int lrow = l >> 2;
    const int lch  = l & 3;
    const int wr = w >> 1, wc = w & 1;
    const int fr = l & 15;
    const int fq = l >> 4;

    f32x4 acc0[4][4] = {};
    f32x4 acc1[4][4] = {};

    for (int k0 = 0; k0 < KTOT; k0 += 32) {
#pragma unroll
        for (int i = 0; i < 4; ++i) {
            const int rb  = w * 4 + i;
            const int row = rb * 16 + lrow;
            const f16* ga = A + (size_t)(n0 + row) * LDA + k0 + lch * 8;
            __builtin_amdgcn_global_load_lds((g_void*)ga, (lds_void*)(sA + rb * 512), 16, 0, 0);
        }
#pragma unroll
        for (int i = 0; i < 2; ++i) {
            const int rb  = w * 2 + i;
            const int row = rb * 16 + lrow;
            const f16* gb0 = B0 + (size_t)(c0 + row) * LDB + k0 + lch * 8;
            __builtin_amdgcn_global_load_lds((g_void*)gb0, (lds_void*)(sB0 + rb * 512), 16, 0, 0);
            if constexpr (NPROD == 2) {
                const f16* gb1 = B1 + (size_t)(c0 + row) * LDB + k0 + lch * 8;
                __builtin_amdgcn_global_load_lds((g_void*)gb1, (lds_void*)(sB1 + rb * 512), 16, 0, 0);
            }
        }
        __syncthreads();

        f16x8 a0[4], a1[4], b0[4], b1[4];
#pragma unroll
        for (int i = 0; i < 4; ++i) {
            a0[i] = *(const f16x8*)(sA + (wr * 64 + i * 16 + fr) * 32 + fq * 8);
            a1[i] = *(const f16x8*)(sA + (128 * 32) + (wr * 64 + i * 16 + fr) * 32 + fq * 8);
            b0[i] = *(const f16x8*)(sB0 + (wc * 64 + i * 16 + fr) * 32 + fq * 8);
            if constexpr (NPROD == 2)
                b1[i] = *(const f16x8*)(sB1 + (wc * 64 + i * 16 + fr) * 32 + fq * 8);
        }

#pragma unroll
        for (int i = 0; i < 4; ++i)
#pragma unroll
            for (int j = 0; j < 4; ++j) {
                acc0[i][j] = __builtin_amdgcn_mfma_f32_16x16x32_f16(a0[i], b0[j], acc0[i][j], 0, 0, 0);
                acc1[i][j] = __builtin_amdgcn_mfma_f32_16x16x32_f16(a1[i], b0[j], acc1[i][j], 0, 0, 0);
                if constexpr (NPROD == 2) {
                    acc0[i][j] = __builtin_amdgcn_mfma_f32_16x16x32_f16(a0[i], b1[j], acc0[i][j], 0, 0, 0);
                    acc1[i][j] = __builtin_amdgcn_mfma_f32_16x16x32_f16(a1[i], b1[j], acc1[i][j], 0, 0, 0);
                }
            }
        __syncthreads();
    }

#pragma unroll
    for (int i = 0; i < 4; ++i)
#pragma unroll
        for (int j = 0; j < 4; ++j)
#pragma unroll
            for (int r = 0; r < 4; ++r) {
                const int row = n0 + wr * 64 + i * 16 + fq * 4 + r;
                const int col = c0 + wc * 64 + j * 16 + fr;
                Ch[(size_t)row * LDC + col] = (f16)acc0[i][j][r];
                Ch[(size_t)(row + 128) * LDC + col] = (f16)acc1[i][j][r];
            }
}

// GEMM1: Yh[z] = f16( x[b] @ Wh[h] ), z=b*4+h. xcd=b. 512 blocks, paired,
// SINGLE product (Wl dropped: W-f16 rounding adds ~3.2e-3 logit noise,
// one of four equal terms — predicted absmax ~0.038 < 0.0494).
__global__ __launch_bounds__(256, 2) void k_g1(
    const f16* __restrict__ xfh, const f16* __restrict__ wTh,
    f16* __restrict__ Yh)
{
    const int i = blockIdx.x;
    const int b = i & 7;
    const int li = i >> 3;            // 0..63
    const int h = li >> 4;
    const int n0 = ((li >> 2) & 3) * 256;
    const int e0 = (li & 3) * 128;
    const int z = b * 4 + h;
    pair_core<1, D_, D_, D_, D_>(
        xfh + (size_t)b * ND,
        wTh + (size_t)h * DD, nullptr,
        Yh + (size_t)z * ND, n0, e0);
}

// GEMM2: S[z] = f16( Yh[z] @ xh[b]^T * scale ). xcd=b. 2048 blocks, single.
__global__ __launch_bounds__(256) void k_g2(
    const f16* __restrict__ Yh, const f16* __restrict__ xfh,
    f16* __restrict__ S)
{
    const int i = blockIdx.x;
    const int b = i & 7;
    const int li = i >> 3;           // 0..255
    const int h = li >> 6;
    const int n0 = ((li >> 3) & 7) * 128;
    const int m0 = (li & 7) * 128;
    const int z = b * 4 + h;
    single_core<D_, D_, N_, D_>(
        Yh + (size_t)z * ND,
        xfh + (size_t)b * ND,
        S + (size_t)z * NN, 0.044194173824159216f, n0, m0);
}

// GEMM4 split-K by head: part[z] = f16( P[z] @ xT[b]^T ). xcd=b. 512 blocks, paired.
__global__ __launch_bounds__(256, 2) void k_g4(
    const f16* __restrict__ P, const f16* __restrict__ xT,
    f16* __restrict__ part)
{
    const int i = blockIdx.x;
    const int b = i & 7;
    const int li = i >> 3;            // 0..63
    const int h = li >> 4;
    const int n0 = ((li >> 2) & 3) * 256;
    const int d0 = (li & 3) * 128;
    const int z = b * 4 + h;
    pair_core<1, N_, N_, D_, N_>(
        P + (size_t)z * NN,
        xT + (size_t)b * ND, nullptr,
        part + (size_t)z * ND, n0, d0);
}

// Reduce: out[b] = 0.25 * sum_h part[b*4+h]   (f16 partials, 8 elems/thread)
__global__ __launch_bounds__(256) void k_reduce(
    const f16* __restrict__ part, float* __restrict__ out)
{
    const int i = blockIdx.x * 256 + threadIdx.x;
    const int b = i / (ND / 8);
    const int r = i - b * (ND / 8);
    const f16x8* p = (const f16x8*)part;
    f16x8 a0 = p[(size_t)(b * 4 + 0) * (ND / 8) + r];
    f16x8 a1 = p[(size_t)(b * 4 + 1) * (ND / 8) + r];
    f16x8 a2 = p[(size_t)(b * 4 + 2) * (ND / 8) + r];
    f16x8 a3 = p[(size_t)(b * 4 + 3) * (ND / 8) + r];
    float4 o0, o1;
    float* o = (float*)&o0;
#pragma unroll
    for (int k = 0; k < 4; ++k)
        o[k] = 0.25f * ((float)a0[k] + (float)a1[k] + (float)a2[k] + (float)a3[k]);
    o = (float*)&o1;
#pragma unroll
    for (int k = 0; k < 4; ++k)
        o[k] = 0.25f * ((float)a0[k+4] + (float)a1[k+4] + (float)a2[k+4] + (float)a3[k+4]);
    ((float4*)out)[(size_t)i * 2]     = o0;
    ((float4*)out)[(size_t)i * 2 + 1] = o1;
}

// Merged decomp: z<8 -> x-batch z (f16 hi + transposed hi); z>=8 -> W head
// z-8 (hi only + transpose). Grid (8,16,12); W part uses y<8 only.
__global__ __launch_bounds__(256) void decomp_xw(
    const float* __restrict__ x, const float* __restrict__ W,
    f16* __restrict__ xfh, f16* __restrict__ xT, f16* __restrict__ wTh)
{
    __shared__ f16 tile[64][65];
    __shared__ float tw[64][65];
    const int t = threadIdx.x;
    const int z = blockIdx.z;
    if (z < 8) {
        const int b = z, n0 = blockIdx.y * 64, d0 = blockIdx.x * 64;
        const float* xb = x + (size_t)b * ND;
#pragma unroll
        for (int p = 0; p < 16; ++p) {
            const int idx = t + p * 256;
            const int r = idx >> 6, c = idx & 63;
            const float v = xb[(size_t)(n0 + r) * D_ + d0 + c];
            const f16 h = (f16)v;
            xfh[(size_t)b * ND + (size_t)(n0 + r) * D_ + d0 + c] = h;
            tile[r][c] = h;
        }
        __syncthreads();
#pragma unroll
        for (int p = 0; p < 16; ++p) {
            const int idx = t + p * 256;
            const int r = idx >> 6, c = idx & 63;
            xT[(size_t)b * ND + (size_t)(d0 + r) * N_ + n0 + c] = tile[c][r];
        }
    } else {
        if (blockIdx.y >= 8) return;
        const int h = z - 8, d0 = blockIdx.y * 64, e0 = blockIdx.x * 64;
        const float* Wh = W + (size_t)h * DD;
#pragma unroll
        for (int p = 0; p < 16; ++p) {
            const int idx = t + p * 256;
            const int r = idx >> 6, c = idx & 63;
            tw[r][c] = Wh[(size_t)(d0 + r) * D_ + e0 + c];
        }
        __syncthreads();
#pragma unroll
        for (int p = 0; p < 16; ++p) {
            const int idx = t + p * 256;
            const int r = idx >> 6, c = idx & 63;
            wTh[(size_t)h * DD + (size_t)(e0 + r) * D_ + d0 + c] = (f16)tw[c][r];
        }
    }
}

// Barrier-free softmax, XCD-aligned: block i -> b = i&7 (same placement as
// the g2 blocks that wrote S[b's z-range]) so S reads hit the local L2.
// One wave per row, 4 rows/block. 8192 blocks.
__global__ __launch_bounds__(256) void softmax_wave(
    const f16* __restrict__ S, f16* __restrict__ P)
{
    const int wave = threadIdx.x >> 6;
    const int l = threadIdx.x & 63;
    const int i = blockIdx.x;
    const int b = i & 7;
    const int li = i >> 3;            // 0..1023
    const int h = li >> 8;            // 0..3
    const int rg = li & 255;          // 0..255 row-group (4 rows)
    const size_t row = (size_t)(b * 4 + h) * N_ + rg * 4 + wave;

    const f16x8* p = (const f16x8*)(S + row * N_);
    f16x8 v0 = p[l * 2], v1 = p[l * 2 + 1];

    float f[16];
#pragma unroll
    for (int k = 0; k < 8; ++k) { f[k] = (float)v0[k]; f[k + 8] = (float)v1[k]; }

    float m = f[0];
#pragma unroll
    for (int k = 1; k < 16; ++k) m = fmaxf(m, f[k]);
#pragma unroll
    for (int o = 32; o > 0; o >>= 1) m = fmaxf(m, __shfl_xor(m, o));

    float s = 0.f;
#pragma unroll
    for (int k = 0; k < 16; ++k) { f[k] = __expf(f[k] - m); s += f[k]; }
#pragma unroll
    for (int o = 32; o > 0; o >>= 1) s += __shfl_xor(s, o);

    const float inv = 1.0f / s;
    f16x8 o0, o1;
#pragma unroll
    for (int k = 0; k < 8; ++k) {
        o0[k] = (f16)(f[k] * inv);
        o1[k] = (f16)(f[k + 8] * inv);
    }
    f16x8* q = (f16x8*)(P + row * N_);
    q[l * 2] = o0;
    q[l * 2 + 1] = o1;
}

extern "C" void kernel_launch(void* const* d_in, const int* in_sizes, int n_in,
                              void* d_out, int out_size, void* d_ws, size_t ws_size,
                              hipStream_t stream) {
    const float* x = (const float*)d_in[0];   // [8,1024,512]
    const float* W = (const float*)d_in[1];   // [4,512,512]
    float* out = (float*)d_out;               // [8,1024,512]

    // workspace layout (proven footprint)
    char* ws = (char*)d_ws;
    const size_t MB = 1024 * 1024;
    f16*   xfh = (f16*)(ws + 0 * MB);     // 8 MiB
    f16*   xT  = (f16*)(ws + 8 * MB);     // 8 MiB
    f16*   wTh = (f16*)(ws + 16 * MB);    // 2 MiB
    f16*   Yh  = (f16*)(ws + 20 * MB);    // 32 MiB (full batch, 32 z)
    f16*   S   = (f16*)(ws + 52 * MB);    // 64 MiB (full batch, f16)
    f16*   P   = (f16*)(ws + 116 * MB);   // 64 MiB (full batch, f16)
    f16*   part = S;                      // g4 partials (32 MiB) reuse S

    decomp_xw<<<dim3(8, 16, 12), 256, 0, stream>>>(x, W, xfh, xT, wTh);

    k_g1<<<dim3(512), 256, 0, stream>>>(xfh, wTh, Yh);
    k_g2<<<dim3(2048), 256, 0, stream>>>(Yh, xfh, S);
    softmax_wave<<<dim3(B_ * H_ * N_ / 4), 256, 0, stream>>>(S, P);
    k_g4<<<dim3(512), 256, 0, stream>>>(P, xT, part);
    k_reduce<<<dim3((B_ * ND / 8) / 256), 256, 0, stream>>>(part, out);
}